// Round 1
// baseline (337.829 us; speedup 1.0000x reference)
//
#include <hip/hip_runtime.h>
#include <cstdint>
#include <cstddef>

typedef unsigned short u16;
typedef __attribute__((ext_vector_type(8))) short bf16x8;
typedef __attribute__((ext_vector_type(4))) float f32x4;
typedef __attribute__((ext_vector_type(8))) unsigned short u16x8;

#define T_TOK 8192
#define H_DIM 1024
#define F_DIM 4096
#define E_NUM 8
#define CAP (T_TOK / E_NUM)

// fp32 -> bf16 round-to-nearest-even
__device__ __forceinline__ u16 f2bf(float f) {
  union { float f; uint32_t u; } v; v.f = f;
  uint32_t r = v.u + 0x7FFFu + ((v.u >> 16) & 1u);
  return (u16)(r >> 16);
}

// tanh-approximate gelu: 0.5x(1+tanh(sqrt(2/pi)(x+0.044715x^3)))
//  = x * (1 - 1/(exp(2z)+1)), z = sqrt(2/pi)(x+0.044715x^3)
__device__ __forceinline__ float gelu_tanh(float x) {
  float z2 = 1.5957691216057308f * (x + 0.044715f * x * x * x); // 2*z
  float e = __expf(z2);
  return x * (1.0f - 1.0f / (e + 1.0f));
}

__device__ __forceinline__ void async_copy16(const void* gsrc, void* ldst) {
  __builtin_amdgcn_global_load_lds(
      (const __attribute__((address_space(1))) uint32_t*)gsrc,
      (__attribute__((address_space(3))) uint32_t*)ldst, 16, 0, 0);
}

// ---- fp32 -> bf16 convert (grid-stride, 8 elems/thread) ----
__global__ __launch_bounds__(256) void k_convert(const float* __restrict__ src,
                                                 u16* __restrict__ dst, long n) {
  long i = ((long)blockIdx.x * 256 + threadIdx.x) * 8;
  long stride = (long)gridDim.x * 256 * 8;
  for (; i < n; i += stride) {
    const float4 a = *(const float4*)(src + i);
    const float4 b = *(const float4*)(src + i + 4);
    u16x8 o;
    o[0] = f2bf(a.x); o[1] = f2bf(a.y); o[2] = f2bf(a.z); o[3] = f2bf(a.w);
    o[4] = f2bf(b.x); o[5] = f2bf(b.y); o[6] = f2bf(b.z); o[7] = f2bf(b.w);
    *(u16x8*)(dst + i) = o;
  }
}

// ---- w2 [E][F][H] fp32 -> w2t [E][H][F] bf16 (tiled transpose) ----
__global__ __launch_bounds__(256) void k_transpose_w2(const float* __restrict__ w2,
                                                      u16* __restrict__ w2t) {
  __shared__ float tile[32][33];
  const int ntH = H_DIM / 32;   // 32
  const int ntF = F_DIM / 32;   // 128
  int bid = blockIdx.x;
  int e = bid / (ntF * ntH);
  int r = bid % (ntF * ntH);
  int f0 = (r / ntH) * 32;
  int h0 = (r % ntH) * 32;
  const float* src = w2 + (size_t)e * F_DIM * H_DIM;
  u16* dst = w2t + (size_t)e * H_DIM * F_DIM;
  int col = threadIdx.x & 31;
  int row8 = threadIdx.x >> 5;  // 0..7
#pragma unroll
  for (int i = 0; i < 4; i++) {
    int row = row8 + i * 8;
    tile[row][col] = src[(size_t)(f0 + row) * H_DIM + h0 + col];
  }
  __syncthreads();
#pragma unroll
  for (int i = 0; i < 4; i++) {
    int row = row8 + i * 8;  // h-local
    dst[(size_t)(h0 + row) * F_DIM + f0 + col] = f2bf(tile[col][row]);
  }
}

// ---- m97-structure GEMM: C[e] = A[e] (MxK) * B[e]^T (KxN), both K-contiguous bf16.
// 128x128 tile, BK=32, 4 waves (2x2), each wave 64x64 = 4x4 frags of 16x16x32.
template <bool GELU_BF16_OUT>
__global__ __launch_bounds__(256) void k_gemm_bt(
    const u16* __restrict__ A,  // [E][M][K] bf16
    const u16* __restrict__ B,  // [E][N][K] bf16
    void* __restrict__ C,       // [E][M][N] (bf16 if GELU_BF16_OUT else f32)
    int M, int N, int K) {
  __shared__ __align__(16) u16 As[128 * 32];
  __shared__ __align__(16) u16 Bs[128 * 32];
  const int e = blockIdx.z;
  const int tm = blockIdx.y;
  const int tn = blockIdx.x;
  const int tid = threadIdx.x;
  const int lane = tid & 63;
  const int wave = tid >> 6;
  const int wm = wave >> 1, wn = wave & 1;
  const u16* Ae = A + (size_t)e * M * K + (size_t)tm * 128 * K;
  const u16* Be = B + (size_t)e * N * K + (size_t)tn * 128 * K;
  const int srow = lane >> 2;       // 0..15 within a 16-row chunk
  const int skk = (lane & 3) * 8;   // k offset 0/8/16/24
  f32x4 acc[4][4] = {};

  for (int k0 = 0; k0 < K; k0 += 32) {
    __syncthreads();  // previous iter's LDS reads done
#pragma unroll
    for (int i = 0; i < 2; i++) {
      const int chunk = wave * 2 + i;       // 0..7, wave-uniform
      const int row = chunk * 16 + srow;
      async_copy16(Ae + (size_t)row * K + k0 + skk, &As[chunk * 512]);
      async_copy16(Be + (size_t)row * K + k0 + skk, &Bs[chunk * 512]);
    }
    __syncthreads();  // staging landed (compiler drains vmcnt before barrier)
    bf16x8 af[4], bf[4];
#pragma unroll
    for (int f = 0; f < 4; f++) {
      af[f] = *(const bf16x8*)&As[(wm * 64 + f * 16 + (lane & 15)) * 32 + (lane >> 4) * 8];
      bf[f] = *(const bf16x8*)&Bs[(wn * 64 + f * 16 + (lane & 15)) * 32 + (lane >> 4) * 8];
    }
#pragma unroll
    for (int fm = 0; fm < 4; fm++)
#pragma unroll
      for (int fn = 0; fn < 4; fn++)
        acc[fm][fn] = __builtin_amdgcn_mfma_f32_16x16x32_bf16(af[fm], bf[fn], acc[fm][fn], 0, 0, 0);
  }

  // C/D layout (m89-verified): col = lane&15, row = (lane>>4)*4 + reg
  const int lr = (lane >> 4) * 4;
  const int lc = lane & 15;
  if constexpr (GELU_BF16_OUT) {
    u16* Ce = (u16*)C + (size_t)e * M * N;
#pragma unroll
    for (int fm = 0; fm < 4; fm++) {
#pragma unroll
      for (int fn = 0; fn < 4; fn++) {
        const int col = tn * 128 + wn * 64 + fn * 16 + lc;
#pragma unroll
        for (int r = 0; r < 4; r++) {
          const int row = tm * 128 + wm * 64 + fm * 16 + lr + r;
          Ce[(size_t)row * N + col] = f2bf(gelu_tanh(acc[fm][fn][r]));
        }
      }
    }
  } else {
    float* Ce = (float*)C + (size_t)e * M * N;
#pragma unroll
    for (int fm = 0; fm < 4; fm++) {
#pragma unroll
      for (int fn = 0; fn < 4; fn++) {
        const int col = tn * 128 + wn * 64 + fn * 16 + lc;
#pragma unroll
        for (int r = 0; r < 4; r++) {
          const int row = tm * 128 + wm * 64 + fm * 16 + lr + r;
          Ce[(size_t)row * N + col] = acc[fm][fn][r];
        }
      }
    }
  }
}

extern "C" void kernel_launch(void* const* d_in, const int* in_sizes, int n_in,
                              void* d_out, int out_size, void* d_ws, size_t ws_size,
                              hipStream_t stream) {
  const float* x = (const float*)d_in[0];
  const float* w1 = (const float*)d_in[1];
  const float* w2 = (const float*)d_in[2];
  // d_in[3] = num_experts (scalar) — fixed E_NUM=8 here.

  u16* ws_x = (u16*)d_ws;                               // [T][H] bf16
  u16* ws_w1 = ws_x + (size_t)T_TOK * H_DIM;            // [E][F][H] bf16
  u16* ws_w2t = ws_w1 + (size_t)E_NUM * F_DIM * H_DIM;  // [E][H][F] bf16
  u16* ws_h = ws_w2t + (size_t)E_NUM * H_DIM * F_DIM;   // [T][F] bf16
  const size_t need =
      ((size_t)T_TOK * H_DIM + 2 * (size_t)E_NUM * F_DIM * H_DIM + (size_t)T_TOK * F_DIM) * 2;
  if (ws_size < need) return;  // insufficient scratch -> clean validation fail

  k_convert<<<1024, 256, 0, stream>>>(x, ws_x, (long)T_TOK * H_DIM);
  k_convert<<<2048, 256, 0, stream>>>(w1, ws_w1, (long)E_NUM * F_DIM * H_DIM);
  k_transpose_w2<<<E_NUM * (F_DIM / 32) * (H_DIM / 32), 256, 0, stream>>>(w2, ws_w2t);
  // GEMM1: h = gelu(x_e @ w1_e^T)  -> [E][CAP][F] bf16
  k_gemm_bt<true><<<dim3(F_DIM / 128, CAP / 128, E_NUM), 256, 0, stream>>>(
      ws_x, ws_w1, ws_h, CAP, F_DIM, H_DIM);
  // GEMM2: out = h_e @ w2t_e^T -> [E][CAP][H] f32
  k_gemm_bt<false><<<dim3(H_DIM / 128, CAP / 128, E_NUM), 256, 0, stream>>>(
      ws_h, ws_w2t, d_out, CAP, H_DIM, F_DIM);
}

// Round 2
// 256.150 us; speedup vs baseline: 1.3189x; 1.3189x over previous
//
#include <hip/hip_runtime.h>
#include <cstdint>
#include <cstddef>

typedef unsigned short u16;
typedef __attribute__((ext_vector_type(8))) short bf16x8;
typedef __attribute__((ext_vector_type(4))) float f32x4;
typedef __attribute__((ext_vector_type(8))) unsigned short u16x8;

#define T_TOK 8192
#define H_DIM 1024
#define F_DIM 4096
#define E_NUM 8
#define CAP (T_TOK / E_NUM)

__device__ __forceinline__ u16 f2bf(float f) {
  union { float f; uint32_t u; } v; v.f = f;
  uint32_t r = v.u + 0x7FFFu + ((v.u >> 16) & 1u);
  return (u16)(r >> 16);
}

__device__ __forceinline__ float gelu_tanh(float x) {
  float z2 = 1.5957691216057308f * (x + 0.044715f * x * x * x);
  float e = __expf(z2);
  return x * (1.0f - 1.0f / (e + 1.0f));
}

__device__ __forceinline__ void async_copy16(const void* gsrc, void* ldst) {
  __builtin_amdgcn_global_load_lds(
      (const __attribute__((address_space(1))) uint32_t*)gsrc,
      (__attribute__((address_space(3))) uint32_t*)ldst, 16, 0, 0);
}

__device__ __forceinline__ void wgbar() {
  asm volatile("" ::: "memory");
  __builtin_amdgcn_s_barrier();
  asm volatile("" ::: "memory");
}

template <int N> __device__ __forceinline__ void vm_wait() {
  if constexpr (N == 0) asm volatile("s_waitcnt vmcnt(0)" ::: "memory");
  else if constexpr (N == 3) asm volatile("s_waitcnt vmcnt(3)" ::: "memory");
  else if constexpr (N == 4) asm volatile("s_waitcnt vmcnt(4)" ::: "memory");
}

// ---- fp32 -> bf16 convert ----
__global__ __launch_bounds__(256) void k_convert(const float* __restrict__ src,
                                                 u16* __restrict__ dst, long n) {
  long i = ((long)blockIdx.x * 256 + threadIdx.x) * 8;
  long stride = (long)gridDim.x * 256 * 8;
  for (; i < n; i += stride) {
    const float4 a = *(const float4*)(src + i);
    const float4 b = *(const float4*)(src + i + 4);
    u16x8 o;
    o[0] = f2bf(a.x); o[1] = f2bf(a.y); o[2] = f2bf(a.z); o[3] = f2bf(a.w);
    o[4] = f2bf(b.x); o[5] = f2bf(b.y); o[6] = f2bf(b.z); o[7] = f2bf(b.w);
    *(u16x8*)(dst + i) = o;
  }
}

// ---- w2 [E][F][H] fp32 -> w2t [E][H][F] bf16 ----
__global__ __launch_bounds__(256) void k_transpose_w2(const float* __restrict__ w2,
                                                      u16* __restrict__ w2t) {
  __shared__ float tile[32][33];
  const int ntH = H_DIM / 32;
  const int ntF = F_DIM / 32;
  int bid = blockIdx.x;
  int e = bid / (ntF * ntH);
  int r = bid % (ntF * ntH);
  int f0 = (r / ntH) * 32;
  int h0 = (r % ntH) * 32;
  const float* src = w2 + (size_t)e * F_DIM * H_DIM;
  u16* dst = w2t + (size_t)e * H_DIM * F_DIM;
  int col = threadIdx.x & 31;
  int row8 = threadIdx.x >> 5;
#pragma unroll
  for (int i = 0; i < 4; i++) {
    int row = row8 + i * 8;
    tile[row][col] = src[(size_t)(f0 + row) * H_DIM + h0 + col];
  }
  __syncthreads();
#pragma unroll
  for (int i = 0; i < 4; i++) {
    int row = row8 + i * 8;
    dst[(size_t)(h0 + row) * F_DIM + f0 + col] = f2bf(tile[col][row]);
  }
}

// ==== 8-phase deep-pipelined GEMM: C = A (MxK) * B^T (B is [N][K]), bf16, K-contig.
// BM=256 fixed, BK=64 (2 k-halves of 32), 8 waves (WM x WN), 512 threads.
// LDS pieces: A[buf][kh] = [256][32] bf16 (16KB), B[buf][kh] = [BN][32].
// Per K-tile: 4 phases (mh, kh) = (q&1, q>>1). Stage stream 6 half-tiles ahead:
//   q0: A_k1(t+1)  q1: B_k1(t+1)  q2: A_k0(t+2)  q3: B_k0(t+2)
// vmcnt(VMC) at each tile end, vmcnt(0) entering last tile. k-slot XOR swizzle
// (slot ^= (row>>1)&3) applied on pre-swizzled global src AND ds_read addr.
template <int BN, int WM, int WN, int NTM, int NTN, int NT, bool GELU>
__global__ __launch_bounds__(512, 2) void k_gemm8(const u16* __restrict__ Ag,
                                                  const u16* __restrict__ Bg,
                                                  void* __restrict__ Cg) {
  constexpr int K = NT * 64;
  constexpr int FM = 256 / (WM * 16);
  constexpr int FN = BN / (WN * 16);
  constexpr int FMH = FM / 2;
  constexpr int PA = 256 * 32;            // u16 per A piece
  constexpr int PB = BN * 32;             // u16 per B piece
  constexpr int ABOFF = 4 * PA;           // B pieces base
  constexpr int BSTG = (BN * 32 * 2) / (512 * 16);  // B stage instr/thread (2 or 1)
  constexpr int VMC = 2 + BSTG;
  constexpr int NTOT = NTN * BN;

  __shared__ __align__(16) u16 lds[ABOFF + 4 * PB];

  const int tid = threadIdx.x;
  const int lane = tid & 63;
  const int wave = tid >> 6;
  const int wm = wave / WN;
  const int wn = wave % WN;

  // bijective XCD swizzle (NWG % 8 == 0) + 4x4 supertile decode
  constexpr int NWG = NTM * NTN;
  const int wg = ((int)blockIdx.x & 7) * (NWG / 8) + ((int)blockIdx.x >> 3);
  constexpr int NSN = NTN / 4;
  const int sup = wg >> 4, win = wg & 15;
  const int mt = (sup / NSN) * 4 + (win >> 2);
  const int nt_ = (sup % NSN) * 4 + (win & 3);

  const int e = mt >> 2;  // BM=256, CAP=1024 -> 4 m-tiles per expert
  const u16* Ae = Ag + (size_t)mt * 256 * K;
  const u16* Be = Bg + (size_t)e * NTOT * K + (size_t)nt_ * BN * K;

  // staging per-lane constants (pre-swizzled source k-slot)
  const int srow = lane >> 2;                                 // 0..15
  const int kswz = (((lane & 3) ^ ((lane >> 3) & 3)) << 3);   // elem offset in khalf

  auto stageA = [&](int t, int kh) {
    u16* dst0 = &lds[((t & 1) * 2 + kh) * PA];
    const u16* src = Ae + (size_t)(t * 64 + kh * 32 + kswz);
#pragma unroll
    for (int j = 0; j < 2; ++j) {
      const int cr = (2 * wave + j) * 16 + srow;
      async_copy16(src + (size_t)cr * K, dst0 + (2 * wave + j) * 512);
    }
  };
  auto stageB = [&](int t, int kh) {
    u16* dst0 = &lds[ABOFF + ((t & 1) * 2 + kh) * PB];
    const u16* src = Be + (size_t)(t * 64 + kh * 32 + kswz);
#pragma unroll
    for (int j = 0; j < BSTG; ++j) {
      const int cr = (BSTG * wave + j) * 16 + srow;
      async_copy16(src + (size_t)cr * K, dst0 + (BSTG * wave + j) * 512);
    }
  };

  // ds_read: row-swizzled slot
  const int frow = lane & 15;
  const int fslot = (((lane >> 4) ^ ((lane >> 1) & 3)) << 3);  // u16 offset in row

  f32x4 acc[FM][FN] = {};

  // prologue: tile0 all 4 slots, tile1 slots A_k0,B_k0
  stageA(0, 0); stageB(0, 0); stageA(0, 1); stageB(0, 1);
  stageA(1, 0); stageB(1, 0);
  vm_wait<VMC>();
  wgbar();

  for (int t = 0; t < NT; ++t) {
    const bool s01 = (t < NT - 1);
    const bool s23 = (t < NT - 2);
    bf16x8 af[FMH], bfr[FN];
#pragma unroll
    for (int q = 0; q < 4; ++q) {
      const int kh = q >> 1, mh = q & 1;
      const u16* pa = &lds[((t & 1) * 2 + kh) * PA];
      const u16* pb = &lds[ABOFF + ((t & 1) * 2 + kh) * PB];
      if (mh == 0) {
#pragma unroll
        for (int i = 0; i < FN; ++i) {
          const int r = wn * (BN / WN) + i * 16 + frow;
          bfr[i] = *(const bf16x8*)&pb[r * 32 + fslot];
        }
      }
#pragma unroll
      for (int i = 0; i < FMH; ++i) {
        const int r = wm * (256 / WM) + (mh * FMH + i) * 16 + frow;
        af[i] = *(const bf16x8*)&pa[r * 32 + fslot];
      }
      if (q == 0) { if (s01) stageA(t + 1, 1); }
      else if (q == 1) { if (s01) stageB(t + 1, 1); }
      else if (q == 2) { if (s23) stageA(t + 2, 0); }
      else { if (s23) stageB(t + 2, 0); }
      wgbar();
      asm volatile("s_waitcnt lgkmcnt(0)" ::: "memory");
      __builtin_amdgcn_sched_barrier(0);
      __builtin_amdgcn_s_setprio(1);
#pragma unroll
      for (int i = 0; i < FMH; ++i)
#pragma unroll
        for (int fn = 0; fn < FN; ++fn)
          acc[mh * FMH + i][fn] = __builtin_amdgcn_mfma_f32_16x16x32_bf16(
              af[i], bfr[fn], acc[mh * FMH + i][fn], 0, 0, 0);
      __builtin_amdgcn_s_setprio(0);
      if (q == 3) {
        if (s23) vm_wait<VMC>(); else vm_wait<0>();
      }
      wgbar();
    }
  }

  // epilogue: C/D layout col=lane&15, row=(lane>>4)*4+reg
  const int lr = (lane >> 4) * 4;
  const int lc = lane & 15;
  const size_t Crow0 = (size_t)mt * 256 + wm * (256 / WM);
  const int Ccol0 = nt_ * BN + wn * (BN / WN);
  if constexpr (GELU) {
    u16* Cp = (u16*)Cg;
#pragma unroll
    for (int fm = 0; fm < FM; ++fm)
#pragma unroll
      for (int fn = 0; fn < FN; ++fn) {
        const int col = Ccol0 + fn * 16 + lc;
#pragma unroll
        for (int r = 0; r < 4; ++r) {
          const size_t row = Crow0 + fm * 16 + lr + r;
          Cp[row * NTOT + col] = f2bf(gelu_tanh(acc[fm][fn][r]));
        }
      }
  } else {
    float* Cp = (float*)Cg;
#pragma unroll
    for (int fm = 0; fm < FM; ++fm)
#pragma unroll
      for (int fn = 0; fn < FN; ++fn) {
        const int col = Ccol0 + fn * 16 + lc;
#pragma unroll
        for (int r = 0; r < 4; ++r) {
          const size_t row = Crow0 + fm * 16 + lr + r;
          Cp[row * NTOT + col] = acc[fm][fn][r];
        }
      }
  }
}

extern "C" void kernel_launch(void* const* d_in, const int* in_sizes, int n_in,
                              void* d_out, int out_size, void* d_ws, size_t ws_size,
                              hipStream_t stream) {
  const float* x = (const float*)d_in[0];
  const float* w1 = (const float*)d_in[1];
  const float* w2 = (const float*)d_in[2];

  u16* ws_x = (u16*)d_ws;                               // [T][H] bf16
  u16* ws_w1 = ws_x + (size_t)T_TOK * H_DIM;            // [E][F][H] bf16
  u16* ws_w2t = ws_w1 + (size_t)E_NUM * F_DIM * H_DIM;  // [E][H][F] bf16
  u16* ws_h = ws_w2t + (size_t)E_NUM * H_DIM * F_DIM;   // [T][F] bf16
  const size_t need =
      ((size_t)T_TOK * H_DIM + 2 * (size_t)E_NUM * F_DIM * H_DIM + (size_t)T_TOK * F_DIM) * 2;
  if (ws_size < need) return;

  k_convert<<<1024, 256, 0, stream>>>(x, ws_x, (long)T_TOK * H_DIM);
  k_convert<<<2048, 256, 0, stream>>>(w1, ws_w1, (long)E_NUM * F_DIM * H_DIM);
  k_transpose_w2<<<E_NUM * (F_DIM / 32) * (H_DIM / 32), 256, 0, stream>>>(w2, ws_w2t);

  // GEMM1: h = gelu(x_e @ w1_e^T) -> [T][F] bf16
  //   BM=256,BN=256, 8 waves 2x4, NTM=32, NTN=16, NT=K/64=16
  k_gemm8<256, 2, 4, 32, 16, 16, true><<<512, 512, 0, stream>>>(ws_x, ws_w1, ws_h);
  // GEMM2: out = h_e @ w2t_e^T -> [T][H] f32
  //   BM=256,BN=128, 8 waves 4x2, NTM=32, NTN=8, NT=4096/64=64
  k_gemm8<128, 4, 2, 32, 8, 64, false><<<256, 512, 0, stream>>>(ws_h, ws_w2t, d_out);
}